// Round 8
// baseline (518.286 us; speedup 1.0000x reference)
//
#include <hip/hip_runtime.h>

typedef unsigned short u16;
typedef __attribute__((ext_vector_type(8))) short vbf16x8;   // 8 bf16 (4 VGPRs)
typedef __attribute__((ext_vector_type(4))) float vf32x4;    // MFMA acc frag

__device__ __forceinline__ float bf2f(u16 u) {
    union { unsigned int i; float f; } v; v.i = ((unsigned int)u) << 16; return v.f;
}
__device__ __forceinline__ u16 f2bf(float f) {
    union { float f; unsigned int i; } v; v.f = f;
    return (u16)((v.i + 0x7fffu + ((v.i >> 16) & 1u)) >> 16);  // RNE
}

struct TPack { const float* src[9]; u16* dst[9]; };

// ================ mega 1: hist + weight transposes + author gather ========
__global__ __launch_bounds__(256) void mega_hist_prep(
    TPack p, const float* __restrict__ emb, const int* __restrict__ ids,
    u16* __restrict__ xauth, int NA,
    const int* __restrict__ src, const int* __restrict__ dst,
    int* __restrict__ cnt, int ND, int E, int prepB) {
    int b = blockIdx.x;
    if (b >= prepB) {                      // ---- histogram part ----
        int e = (b - prepB) * 256 + threadIdx.x;
        if (e < E) {
            atomicAdd(cnt + src[e], 1);
            atomicAdd(cnt + ND + dst[e], 1);
        }
        return;
    }
    if (b < 576) {                         // ---- 9 mats x 64 blocks ----
        int mat = b / 64;
        const float* s = p.src[mat];
        u16* d = p.dst[mat];
        int i = (b % 64) * 256 + threadIdx.x;
        int k = i >> 7, n = i & 127;
        d[(size_t)n * 128 + k] = f2bf(s[(size_t)k * 128 + n]);
    } else {                               // ---- author row gather ----
        int gid = (b - 576) * 256 + threadIdx.x;
        if (gid >= NA * 16) return;
        int n = gid >> 4, f = gid & 15;
        int id = ids[n];
        const float* s = emb + (size_t)id * 128 + f * 8;
        float4 lo = *(const float4*)(s);
        float4 hi = *(const float4*)(s + 4);
        u16 o[8] = {f2bf(lo.x), f2bf(lo.y), f2bf(lo.z), f2bf(lo.w),
                    f2bf(hi.x), f2bf(hi.y), f2bf(hi.z), f2bf(hi.w)};
        *(uint4*)(xauth + (size_t)n * 128 + f * 8) = *(const uint4*)o;
    }
}

// ======= scan 1+2 fused: per-256-block inclusive scan; last block scans bs =
__global__ __launch_bounds__(256) void scan12b(
    const int* __restrict__ cnt, int* __restrict__ incl,
    int* __restrict__ bs, int* __restrict__ ctr,
    int ND, int NA, int NBD, int NBA) {
    __shared__ int sh[256];
    __shared__ int lastFlag;
    __shared__ int carry;
    int b = blockIdx.x, tid = threadIdx.x;
    const int* in; int* out; int N; int lb;
    if (b < NBD) { in = cnt;      out = incl;      N = ND; lb = b; }
    else         { in = cnt + ND; out = incl + ND; N = NA; lb = b - NBD; }
    int gid = lb * 256 + tid;
    int v = gid < N ? in[gid] : 0;
    sh[tid] = v; __syncthreads();
    for (int off = 1; off < 256; off <<= 1) {
        int t = tid >= off ? sh[tid - off] : 0; __syncthreads();
        sh[tid] += t; __syncthreads();
    }
    if (gid < N) out[gid] = sh[tid];
    if (tid == 255) bs[b] = sh[255];
    // ---- last-block detection (device-scope atomic + fences) ----
    __threadfence();
    __syncthreads();
    if (tid == 0) lastFlag = (atomicAdd(ctr, 1) == NBD + NBA - 1);
    __syncthreads();
    if (!lastFlag) return;
    __threadfence();                       // acquire: all bs[] stores visible
    // ---- exclusive scan of block sums, both segments ----
    for (int seg = 0; seg < 2; ++seg) {
        int* p = seg ? bs + NBD : bs;
        int nb = seg ? NBA : NBD;
        if (tid == 0) carry = 0;
        __syncthreads();
        for (int base = 0; base < nb; base += 256) {
            int i = base + tid;
            int x = i < nb ? p[i] : 0;
            sh[tid] = x; __syncthreads();
            for (int off = 1; off < 256; off <<= 1) {
                int t = tid >= off ? sh[tid - off] : 0; __syncthreads();
                sh[tid] += t; __syncthreads();
            }
            if (i < nb) p[i] = carry + sh[tid] - x;   // exclusive
            __syncthreads();
            if (tid == 255) carry += sh[255];
            __syncthreads();
        }
    }
}

// ====== scan3 (+cursor seed) fused with doc encoder GEMM ==================
// blocks [0, scanB): offsets finalize; blocks [scanB, scanB+BD): doc_gemm.
__global__ __launch_bounds__(256) void scan3_docgemm(
    const int* __restrict__ incl, const int* __restrict__ bs,
    int* __restrict__ offs_d, int* __restrict__ offs_a,
    int* __restrict__ cur_d, int* __restrict__ cur_a,
    int ND, int NA, int NBD, int scanB,
    const float* __restrict__ A1f, const u16* __restrict__ W1T,
    const float* __restrict__ bias, u16* __restrict__ out, const int M) {
    __shared__ u16 WS[128 * 128];   // 32 KB (doc part)
    const int b = blockIdx.x;
    if (b < scanB) {                       // ---- scan3: offs + cursor seed --
        int tid = threadIdx.x;
        if (b < NBD) {
            int gid = b * 256 + tid;
            if (gid < ND) {
                int v = incl[gid] + bs[b];
                offs_d[gid + 1] = v; cur_d[gid + 1] = v;
            }
            if (gid == 0) { offs_d[0] = 0; cur_d[0] = 0; }
        } else {
            int gid = (b - NBD) * 256 + tid;
            if (gid < NA) {
                int v = incl[ND + gid] + bs[b];
                offs_a[gid + 1] = v; cur_a[gid + 1] = v;
            }
            if (gid == 0) { offs_a[0] = 0; cur_a[0] = 0; }
        }
        return;
    }
    // ---- doc_gemm: 256-row block, 4 waves x 64 rows ----
    const int tid = threadIdx.x;
    const int lane = tid & 63, wave = tid >> 6;
    const int r15 = lane & 15, kq = lane >> 4;
    const int rowbase = (b - scanB) * 256 + wave * 64;
    bool v[4]; int m[4];
#pragma unroll
    for (int j = 0; j < 4; ++j) { m[j] = rowbase + j * 16 + r15; v[j] = rowbase + j * 16 < M; }

    vf32x4 acc[4][8];
#pragma unroll
    for (int j = 0; j < 4; ++j)
#pragma unroll
        for (int i = 0; i < 8; ++i) acc[j][i] = (vf32x4)(0.0f);

#pragma unroll
    for (int i = 0; i < 8; ++i) {
        int L = i * 256 + tid;
        int n = L >> 4, bk = L & 15;
        uint4 vv = *(const uint4*)(W1T + (size_t)L * 8);
        *(uint4*)(WS + ((size_t)n * 16 + (bk ^ (n & 15))) * 8) = vv;
    }
    __syncthreads();

#pragma unroll
    for (int ks = 0; ks < 4; ++ks) {
        vbf16x8 a[4];
#pragma unroll
        for (int j = 0; j < 4; ++j) {
            a[j] = (vbf16x8)(short)0;
            if (v[j]) {
                const float* p = A1f + (size_t)m[j] * 128 + ks * 32 + kq * 8;
                float4 lo = *(const float4*)p, hi = *(const float4*)(p + 4);
                a[j][0] = (short)f2bf(lo.x); a[j][1] = (short)f2bf(lo.y);
                a[j][2] = (short)f2bf(lo.z); a[j][3] = (short)f2bf(lo.w);
                a[j][4] = (short)f2bf(hi.x); a[j][5] = (short)f2bf(hi.y);
                a[j][6] = (short)f2bf(hi.z); a[j][7] = (short)f2bf(hi.w);
            }
        }
#pragma unroll
        for (int nt = 0; nt < 8; ++nt) {
            vbf16x8 bb = *(const vbf16x8*)(
                WS + ((size_t)(nt * 16 + r15) * 16 + ((ks * 4 + kq) ^ r15)) * 8);
#pragma unroll
            for (int j = 0; j < 4; ++j)
                acc[j][nt] = __builtin_amdgcn_mfma_f32_16x16x32_bf16(a[j], bb, acc[j][nt], 0, 0, 0);
        }
    }

#pragma unroll
    for (int nt = 0; nt < 8; ++nt) {
        const float bv = bias[nt * 16 + r15];
#pragma unroll
        for (int j = 0; j < 4; ++j) {
            if (!v[j]) continue;
#pragma unroll
            for (int r = 0; r < 4; ++r)
                out[(size_t)(rowbase + j * 16 + kq * 4 + r) * 128 + nt * 16 + r15] =
                    f2bf(acc[j][nt][r] + bv);
        }
    }
}

// fill via pre-seeded cursors (no LDS, high occupancy)
__global__ __launch_bounds__(256) void fill_kernel(
    const int* __restrict__ src, const int* __restrict__ dst,
    int* __restrict__ cur_d, int* __restrict__ cur_a,
    int* __restrict__ nbr_d, int* __restrict__ nbr_a, int E) {
    int e = blockIdx.x * 256 + threadIdx.x;
    if (e >= E) return;
    int s = src[e], d = dst[e];
    nbr_d[atomicAdd(cur_d + s, 1)] = d;   // doc's author neighbors
    nbr_a[atomicAdd(cur_a + d, 1)] = s;   // author's doc neighbors
}

// ================= gather mean-aggregation: ONE WAVE PER NODE =============
// lane = (nb in 0..3, f in 0..15): neighbor slot nb, feature octet f.
// 4 neighbors in flight per step, zero intra-wave divergence; cross-slot
// reduce via shfl_xor(16/32). nodes [0,NA)=author side, [NA,NA+ND)=doc side.
__global__ __launch_bounds__(256) void agg_mean2(
    const u16* __restrict__ xa, const int* __restrict__ offs_a,
    const int* __restrict__ nbr_a, u16* __restrict__ outa, int NA,
    const u16* __restrict__ xd, const int* __restrict__ offs_d,
    const int* __restrict__ nbr_d, u16* __restrict__ outd, int ND) {
    int wid = (blockIdx.x * 256 + threadIdx.x) >> 6;
    int lane = threadIdx.x & 63;
    int nb = lane >> 4, f = lane & 15;
    int node = wid;
    const u16* x; const int* offs; const int* nbr; u16* out;
    if (node < NA) { x = xa; offs = offs_a; nbr = nbr_a; out = outa; }
    else {
        node -= NA;
        if (node >= ND) return;            // whole-wave uniform exit
        x = xd; offs = offs_d; nbr = nbr_d; out = outd;
    }
    int beg = offs[node], end = offs[node + 1];
    float acc[8] = {0, 0, 0, 0, 0, 0, 0, 0};
    int i = beg + nb;
    for (; i + 4 < end; i += 8) {          // 2 neighbors in flight per lane
        int s0 = nbr[i], s1 = nbr[i + 4];
        uint4 q0 = *(const uint4*)(x + (size_t)s0 * 128 + f * 8);
        uint4 q1 = *(const uint4*)(x + (size_t)s1 * 128 + f * 8);
        acc[0] += bf2f((u16)(q0.x & 0xffff)) + bf2f((u16)(q1.x & 0xffff));
        acc[1] += bf2f((u16)(q0.x >> 16))    + bf2f((u16)(q1.x >> 16));
        acc[2] += bf2f((u16)(q0.y & 0xffff)) + bf2f((u16)(q1.y & 0xffff));
        acc[3] += bf2f((u16)(q0.y >> 16))    + bf2f((u16)(q1.y >> 16));
        acc[4] += bf2f((u16)(q0.z & 0xffff)) + bf2f((u16)(q1.z & 0xffff));
        acc[5] += bf2f((u16)(q0.z >> 16))    + bf2f((u16)(q1.z >> 16));
        acc[6] += bf2f((u16)(q0.w & 0xffff)) + bf2f((u16)(q1.w & 0xffff));
        acc[7] += bf2f((u16)(q0.w >> 16))    + bf2f((u16)(q1.w >> 16));
    }
    if (i < end) {
        int s0 = nbr[i];
        uint4 q0 = *(const uint4*)(x + (size_t)s0 * 128 + f * 8);
        acc[0] += bf2f((u16)(q0.x & 0xffff));
        acc[1] += bf2f((u16)(q0.x >> 16));
        acc[2] += bf2f((u16)(q0.y & 0xffff));
        acc[3] += bf2f((u16)(q0.y >> 16));
        acc[4] += bf2f((u16)(q0.z & 0xffff));
        acc[5] += bf2f((u16)(q0.z >> 16));
        acc[6] += bf2f((u16)(q0.w & 0xffff));
        acc[7] += bf2f((u16)(q0.w >> 16));
    }
    // reduce the 4 neighbor slots (lanes f, f+16, f+32, f+48)
#pragma unroll
    for (int j = 0; j < 8; ++j) {
        acc[j] += __shfl_xor(acc[j], 16);
        acc[j] += __shfl_xor(acc[j], 32);
    }
    if (nb == 0) {
        float inv = 1.0f / fmaxf((float)(end - beg), 1.0f);
        u16 o[8];
#pragma unroll
        for (int j = 0; j < 8; ++j) o[j] = f2bf(acc[j] * inv);
        *(uint4*)(out + (size_t)node * 128 + f * 8) = *(const uint4*)o;
    }
}

// ---------------- fused dual-side SAGE conv GEMM (64-row wave tile) -------
struct SideParams {
    const u16* A1b; const u16* W1T;
    const u16* A2b; const u16* W2T;
    const float* bias; u16* out;
    int M; int do_relu; int nblocks;
};
__global__ __launch_bounds__(256) void conv_gemm2(SideParams sa, SideParams sd) {
    __shared__ u16 WS[128 * 128];   // 32 KB
    const bool isA = (int)blockIdx.x < sa.nblocks;
    SideParams P = isA ? sa : sd;
    const int bx = isA ? blockIdx.x : blockIdx.x - sa.nblocks;
    const int tid = threadIdx.x;
    const int lane = tid & 63, wave = tid >> 6;
    const int r15 = lane & 15, kq = lane >> 4;
    const int rowbase = bx * 256 + wave * 64;
    bool v[4]; int m[4];
#pragma unroll
    for (int j = 0; j < 4; ++j) { m[j] = rowbase + j * 16 + r15; v[j] = rowbase + j * 16 < P.M; }

    vf32x4 acc[4][8];
#pragma unroll
    for (int j = 0; j < 4; ++j)
#pragma unroll
        for (int i = 0; i < 8; ++i) acc[j][i] = (vf32x4)(0.0f);

#pragma unroll
    for (int mat = 0; mat < 2; ++mat) {
        const u16* WT = mat ? P.W2T : P.W1T;
        if (mat) __syncthreads();          // protect WS before overwrite
#pragma unroll
        for (int i = 0; i < 8; ++i) {
            int L = i * 256 + tid;
            int n = L >> 4, bk = L & 15;
            uint4 vv = *(const uint4*)(WT + (size_t)L * 8);
            *(uint4*)(WS + ((size_t)n * 16 + (bk ^ (n & 15))) * 8) = vv;
        }
        __syncthreads();

        const u16* Ab = mat ? P.A2b : P.A1b;
#pragma unroll
        for (int ks = 0; ks < 4; ++ks) {
            vbf16x8 a[4];
#pragma unroll
            for (int j = 0; j < 4; ++j) {
                a[j] = (vbf16x8)(short)0;
                if (v[j]) a[j] = *(const vbf16x8*)(Ab + (size_t)m[j] * 128 + ks * 32 + kq * 8);
            }
#pragma unroll
            for (int nt = 0; nt < 8; ++nt) {
                vbf16x8 b = *(const vbf16x8*)(
                    WS + ((size_t)(nt * 16 + r15) * 16 + ((ks * 4 + kq) ^ r15)) * 8);
#pragma unroll
                for (int j = 0; j < 4; ++j)
                    acc[j][nt] = __builtin_amdgcn_mfma_f32_16x16x32_bf16(a[j], b, acc[j][nt], 0, 0, 0);
            }
        }
    }

#pragma unroll
    for (int nt = 0; nt < 8; ++nt) {
        const float bv = P.bias[nt * 16 + r15];
#pragma unroll
        for (int j = 0; j < 4; ++j) {
            if (!v[j]) continue;
#pragma unroll
            for (int r = 0; r < 4; ++r) {
                float val = acc[j][nt][r] + bv;
                if (P.do_relu) val = fmaxf(val, 0.0f);
                P.out[(size_t)(rowbase + j * 16 + kq * 4 + r) * 128 + nt * 16 + r15] = f2bf(val);
            }
        }
    }
}

// ---------------- edge scorer: pred[e] = dot(od[i0[e]], oa[i1[e]]) --------
__global__ __launch_bounds__(256) void edge_dot(
    const u16* __restrict__ od, const u16* __restrict__ oa,
    const int* __restrict__ i0, const int* __restrict__ i1,
    float* __restrict__ pred, int EL) {
    int gid = blockIdx.x * 256 + threadIdx.x;
    if (gid >= EL * 16) return;
    int e = gid >> 4, f = gid & 15;
    uint4 x = *(const uint4*)(od + (size_t)i0[e] * 128 + f * 8);
    uint4 y = *(const uint4*)(oa + (size_t)i1[e] * 128 + f * 8);
    float s = 0.0f;
    s += bf2f((u16)(x.x & 0xffff)) * bf2f((u16)(y.x & 0xffff));
    s += bf2f((u16)(x.x >> 16))    * bf2f((u16)(y.x >> 16));
    s += bf2f((u16)(x.y & 0xffff)) * bf2f((u16)(y.y & 0xffff));
    s += bf2f((u16)(x.y >> 16))    * bf2f((u16)(y.y >> 16));
    s += bf2f((u16)(x.z & 0xffff)) * bf2f((u16)(y.z & 0xffff));
    s += bf2f((u16)(x.z >> 16))    * bf2f((u16)(y.z >> 16));
    s += bf2f((u16)(x.w & 0xffff)) * bf2f((u16)(y.w & 0xffff));
    s += bf2f((u16)(x.w >> 16))    * bf2f((u16)(y.w >> 16));
    s += __shfl_xor(s, 1);
    s += __shfl_xor(s, 2);
    s += __shfl_xor(s, 4);
    s += __shfl_xor(s, 8);
    if (f == 0) pred[e] = s;
}

extern "C" void kernel_launch(void* const* d_in, const int* in_sizes, int n_in,
                              void* d_out, int out_size, void* d_ws, size_t ws_size,
                              hipStream_t stream) {
    const float* doc_x    = (const float*)d_in[0];
    const int*   auth_id  = (const int*)d_in[1];
    const int*   eidx     = (const int*)d_in[2];
    const int*   elidx    = (const int*)d_in[3];
    const float* W_doc    = (const float*)d_in[4];
    const float* b_doc    = (const float*)d_in[5];
    const float* emb      = (const float*)d_in[6];
    const float* c1_da_Wl = (const float*)d_in[7];
    const float* c1_da_bl = (const float*)d_in[8];
    const float* c1_da_Wr = (const float*)d_in[9];
    const float* c1_ad_Wl = (const float*)d_in[10];
    const float* c1_ad_bl = (const float*)d_in[11];
    const float* c1_ad_Wr = (const float*)d_in[12];
    const float* c2_da_Wl = (const float*)d_in[13];
    const float* c2_da_bl = (const float*)d_in[14];
    const float* c2_da_Wr = (const float*)d_in[15];
    const float* c2_ad_Wl = (const float*)d_in[16];
    const float* c2_ad_bl = (const float*)d_in[17];
    const float* c2_ad_Wr = (const float*)d_in[18];

    const int ND = in_sizes[0] / 128;
    const int NA = in_sizes[1];
    const int E  = in_sizes[2] / 2;
    const int EL = in_sizes[3] / 2;
    const int* e_src = eidx;        // doc endpoints
    const int* e_dst = eidx + E;    // author endpoints
    const int NBD = (ND + 255) / 256, NBA = (NA + 255) / 256;
    const int BA = (NA + 255) / 256, BD = (ND + 255) / 256;   // 256-row tiles
    const int histB = (E + 255) / 256;
    const int prepB = 576 + (NA * 16 + 255) / 256;

    // ---- workspace layout ----
    char* base = (char*)d_ws;
    size_t off = 0;
    auto alloc = [&](size_t bytes) {
        void* p = base + off;
        off = (off + bytes + 255) & ~(size_t)255;
        return p;
    };
    u16*  xdoc  = (u16*)alloc((size_t)ND * 128 * 2);   // later reused as o_d
    u16*  xauth = (u16*)alloc((size_t)NA * 128 * 2);   // later reused as o_a
    u16*  hd    = (u16*)alloc((size_t)ND * 128 * 2);
    u16*  ha    = (u16*)alloc((size_t)NA * 128 * 2);
    u16*  aggA  = (u16*)alloc((size_t)NA * 128 * 2);
    u16*  aggD  = (u16*)alloc((size_t)ND * 128 * 2);
    u16*  wt    = (u16*)alloc((size_t)9 * 128 * 128 * 2);
    int*  cnt   = (int*)alloc((size_t)(ND + NA + 64) * 4);   // + ctr tail
    int*  ctr   = cnt + ND + NA;
    int*  incl  = (int*)alloc((size_t)(ND + NA) * 4);
    int*  bs    = (int*)alloc((size_t)(NBD + NBA) * 4);
    int*  offs_d = (int*)alloc((size_t)(ND + 1) * 4);
    int*  offs_a = (int*)alloc((size_t)(NA + 1) * 4);
    int*  cur_d = (int*)alloc((size_t)(ND + 1) * 4);
    int*  cur_a = (int*)alloc((size_t)(NA + 1) * 4);
    int*  nbr_d = (int*)alloc((size_t)E * 4);
    int*  nbr_a = (int*)alloc((size_t)E * 4);
    (void)ws_size; (void)n_in; (void)out_size;
    u16* od = xdoc;   // layer-2 outputs overwrite layer-0 features
    u16* oa = xauth;

    TPack tp;
    const float* srcs[9] = {W_doc, c1_da_Wl, c1_da_Wr, c1_ad_Wl, c1_ad_Wr,
                            c2_da_Wl, c2_da_Wr, c2_ad_Wl, c2_ad_Wr};
    for (int i = 0; i < 9; ++i) { tp.src[i] = srcs[i]; tp.dst[i] = wt + (size_t)i * 16384; }
    const u16 *WTdoc = wt, *WT_c1daL = wt + 16384, *WT_c1daR = wt + 2 * 16384,
              *WT_c1adL = wt + 3 * 16384, *WT_c1adR = wt + 4 * 16384,
              *WT_c2daL = wt + 5 * 16384, *WT_c2daR = wt + 6 * 16384,
              *WT_c2adL = wt + 7 * 16384, *WT_c2adR = wt + 8 * 16384;

    // ---- CSR count + prep (one dispatch); memset also zeroes ctr ----
    hipMemsetAsync(cnt, 0, (size_t)(ND + NA + 64) * 4, stream);
    mega_hist_prep<<<prepB + histB, 256, 0, stream>>>(
        tp, emb, auth_id, xauth, NA, e_src, e_dst, cnt, ND, E, prepB);

    // ---- scan 1+2 fused ----
    scan12b<<<NBD + NBA, 256, 0, stream>>>(cnt, incl, bs, ctr, ND, NA, NBD, NBA);

    // ---- scan3 + cursor seed + doc encoder (doc blocks trail) ----
    scan3_docgemm<<<NBD + NBA + BD, 256, 0, stream>>>(
        incl, bs, offs_d, offs_a, cur_d, cur_a, ND, NA, NBD, NBD + NBA,
        doc_x, WTdoc, b_doc, xdoc, ND);

    // ---- CSR fill (no LDS, high occupancy) ----
    fill_kernel<<<histB, 256, 0, stream>>>(
        e_src, e_dst, cur_d, cur_a, nbr_d, nbr_a, E);

    const int aggB = (NA + ND + 3) / 4;    // one wave per node

    // ---- layer 1 (relu) ----
    agg_mean2<<<aggB, 256, 0, stream>>>(
        xdoc, offs_a, nbr_a, aggA, NA, xauth, offs_d, nbr_d, aggD, ND);
    {
        SideParams sa = {aggA, WT_c1daL, xauth, WT_c1daR, c1_da_bl, ha, NA, 1, BA};
        SideParams sd = {aggD, WT_c1adL, xdoc,  WT_c1adR, c1_ad_bl, hd, ND, 1, BD};
        conv_gemm2<<<BA + BD, 256, 0, stream>>>(sa, sd);
    }

    // ---- layer 2 ----
    agg_mean2<<<aggB, 256, 0, stream>>>(
        hd, offs_a, nbr_a, aggA, NA, ha, offs_d, nbr_d, aggD, ND);
    {
        SideParams sa = {aggA, WT_c2daL, ha, WT_c2daR, c2_da_bl, oa, NA, 0, BA};
        SideParams sd = {aggD, WT_c2adL, hd, WT_c2adR, c2_ad_bl, od, ND, 0, BD};
        conv_gemm2<<<BA + BD, 256, 0, stream>>>(sa, sd);
    }

    // ---- edge scorer ----
    edge_dot<<<(EL * 16 + 255) / 256, 256, 0, stream>>>(
        od, oa, elidx, elidx + EL, (float*)d_out, EL);
}

// Round 9
// 448.756 us; speedup vs baseline: 1.1549x; 1.1549x over previous
//
#include <hip/hip_runtime.h>

typedef unsigned short u16;
typedef __attribute__((ext_vector_type(8))) short vbf16x8;   // 8 bf16 (4 VGPRs)
typedef __attribute__((ext_vector_type(4))) float vf32x4;    // MFMA acc frag

__device__ __forceinline__ float bf2f(u16 u) {
    union { unsigned int i; float f; } v; v.i = ((unsigned int)u) << 16; return v.f;
}
__device__ __forceinline__ u16 f2bf(float f) {
    union { float f; unsigned int i; } v; v.f = f;
    return (u16)((v.i + 0x7fffu + ((v.i >> 16) & 1u)) >> 16);  // RNE
}

struct TPack { const float* src[9]; u16* dst[9]; };

// ================ mega 1: hist + weight transposes + author gather ========
__global__ __launch_bounds__(256) void mega_hist_prep(
    TPack p, const float* __restrict__ emb, const int* __restrict__ ids,
    u16* __restrict__ xauth, int NA,
    const int* __restrict__ src, const int* __restrict__ dst,
    int* __restrict__ cnt, int ND, int E, int prepB) {
    int b = blockIdx.x;
    if (b >= prepB) {                      // ---- histogram part ----
        int e = (b - prepB) * 256 + threadIdx.x;
        if (e < E) {
            atomicAdd(cnt + src[e], 1);
            atomicAdd(cnt + ND + dst[e], 1);
        }
        return;
    }
    if (b < 576) {                         // ---- 9 mats x 64 blocks ----
        int mat = b / 64;
        const float* s = p.src[mat];
        u16* d = p.dst[mat];
        int i = (b % 64) * 256 + threadIdx.x;
        int k = i >> 7, n = i & 127;
        d[(size_t)n * 128 + k] = f2bf(s[(size_t)k * 128 + n]);
    } else {                               // ---- author row gather ----
        int gid = (b - 576) * 256 + threadIdx.x;
        if (gid >= NA * 16) return;
        int n = gid >> 4, f = gid & 15;
        int id = ids[n];
        const float* s = emb + (size_t)id * 128 + f * 8;
        float4 lo = *(const float4*)(s);
        float4 hi = *(const float4*)(s + 4);
        u16 o[8] = {f2bf(lo.x), f2bf(lo.y), f2bf(lo.z), f2bf(lo.w),
                    f2bf(hi.x), f2bf(hi.y), f2bf(hi.z), f2bf(hi.w)};
        *(uint4*)(xauth + (size_t)n * 128 + f * 8) = *(const uint4*)o;
    }
}

// batched inclusive scan within 256-blocks + block sums (d then a segment)
__global__ __launch_bounds__(256) void scan1b(
    const int* __restrict__ cnt, int* __restrict__ incl,
    int* __restrict__ bs, int ND, int NA, int NBD) {
    __shared__ int sh[256];
    int b = blockIdx.x, tid = threadIdx.x;
    const int* in; int* out; int N; int lb;
    if (b < NBD) { in = cnt;      out = incl;      N = ND; lb = b; }
    else         { in = cnt + ND; out = incl + ND; N = NA; lb = b - NBD; }
    int gid = lb * 256 + tid;
    int v = gid < N ? in[gid] : 0;
    sh[tid] = v; __syncthreads();
    for (int off = 1; off < 256; off <<= 1) {
        int t = tid >= off ? sh[tid - off] : 0; __syncthreads();
        sh[tid] += t; __syncthreads();
    }
    if (gid < N) out[gid] = sh[tid];
    if (tid == 255) bs[b] = sh[255];
}

// single-block exclusive scan of block sums, both segments
__global__ __launch_bounds__(256) void scan2b(int* __restrict__ bs, int NBD, int NBA) {
    __shared__ int sh[256];
    __shared__ int carry;
    int tid = threadIdx.x;
    for (int seg = 0; seg < 2; ++seg) {
        int* p = seg ? bs + NBD : bs;
        int nb = seg ? NBA : NBD;
        if (tid == 0) carry = 0;
        __syncthreads();
        for (int base = 0; base < nb; base += 256) {
            int i = base + tid;
            int v = i < nb ? p[i] : 0;
            sh[tid] = v; __syncthreads();
            for (int off = 1; off < 256; off <<= 1) {
                int t = tid >= off ? sh[tid - off] : 0; __syncthreads();
                sh[tid] += t; __syncthreads();
            }
            if (i < nb) p[i] = carry + sh[tid] - v;   // exclusive
            __syncthreads();
            if (tid == 255) carry += sh[255];
            __syncthreads();
        }
    }
}

// offs[gid+1] = incl[gid] + block_offset ; offs[0] = 0. Seeds fill cursors.
__global__ __launch_bounds__(256) void scan3b(
    const int* __restrict__ incl, const int* __restrict__ bs,
    int* __restrict__ offs_d, int* __restrict__ offs_a,
    int* __restrict__ cur_d, int* __restrict__ cur_a,
    int ND, int NA, int NBD) {
    int b = blockIdx.x, tid = threadIdx.x;
    if (b < NBD) {
        int gid = b * 256 + tid;
        if (gid < ND) {
            int v = incl[gid] + bs[b];
            offs_d[gid + 1] = v; cur_d[gid + 1] = v;
        }
        if (gid == 0) { offs_d[0] = 0; cur_d[0] = 0; }
    } else {
        int gid = (b - NBD) * 256 + tid;
        if (gid < NA) {
            int v = incl[ND + gid] + bs[b];
            offs_a[gid + 1] = v; cur_a[gid + 1] = v;
        }
        if (gid == 0) { offs_a[0] = 0; cur_a[0] = 0; }
    }
}

// fill via pre-seeded cursors (no LDS, high occupancy)
__global__ __launch_bounds__(256) void fill_kernel(
    const int* __restrict__ src, const int* __restrict__ dst,
    int* __restrict__ cur_d, int* __restrict__ cur_a,
    int* __restrict__ nbr_d, int* __restrict__ nbr_a, int E) {
    int e = blockIdx.x * 256 + threadIdx.x;
    if (e >= E) return;
    int s = src[e], d = dst[e];
    nbr_d[atomicAdd(cur_d + s, 1)] = d;   // doc's author neighbors
    nbr_a[atomicAdd(cur_a + d, 1)] = s;   // author's doc neighbors
}

// ================= fused gather mean-aggregation (both sides) =============
// 16 lanes per node (4 nodes/wave). Batched gather: lane f preloads
// nbr[i+f] (coalesced 64B/group), indices broadcast via shfl, rows gathered
// 4-at-a-time for ILP. nodes [0,NA)=author side, [NA,NA+ND)=doc side.
__global__ __launch_bounds__(256) void agg_mean2(
    const u16* __restrict__ xa, const int* __restrict__ offs_a,
    const int* __restrict__ nbr_a, u16* __restrict__ outa, int NA,
    const u16* __restrict__ xd, const int* __restrict__ offs_d,
    const int* __restrict__ nbr_d, u16* __restrict__ outd, int ND) {
    int gid = blockIdx.x * 256 + threadIdx.x;
    int node = gid >> 4, f = gid & 15;
    int lane = threadIdx.x & 63;
    int gbase = lane & 48;                 // group base lane within wave
    const u16* x; const int* offs; const int* nbr; u16* out;
    if (node < NA) { x = xa; offs = offs_a; nbr = nbr_a; out = outa; }
    else {
        node -= NA;
        if (node >= ND) return;
        x = xd; offs = offs_d; nbr = nbr_d; out = outd;
    }
    int beg = offs[node], end = offs[node + 1];
    float acc[8] = {0, 0, 0, 0, 0, 0, 0, 0};

    for (int i = beg; i < end; i += 16) {
        int cnt = end - i; if (cnt > 16) cnt = 16;
        int myn = (i + f < end) ? nbr[i + f] : 0;
        int t = 0;
        for (; t + 3 < cnt; t += 4) {      // 4 row-gathers in flight
            int i0 = __shfl(myn, gbase + t);
            int i1 = __shfl(myn, gbase + t + 1);
            int i2 = __shfl(myn, gbase + t + 2);
            int i3 = __shfl(myn, gbase + t + 3);
            uint4 q0 = *(const uint4*)(x + (size_t)i0 * 128 + f * 8);
            uint4 q1 = *(const uint4*)(x + (size_t)i1 * 128 + f * 8);
            uint4 q2 = *(const uint4*)(x + (size_t)i2 * 128 + f * 8);
            uint4 q3 = *(const uint4*)(x + (size_t)i3 * 128 + f * 8);
            acc[0] += bf2f((u16)(q0.x & 0xffff)) + bf2f((u16)(q1.x & 0xffff))
                    + bf2f((u16)(q2.x & 0xffff)) + bf2f((u16)(q3.x & 0xffff));
            acc[1] += bf2f((u16)(q0.x >> 16))    + bf2f((u16)(q1.x >> 16))
                    + bf2f((u16)(q2.x >> 16))    + bf2f((u16)(q3.x >> 16));
            acc[2] += bf2f((u16)(q0.y & 0xffff)) + bf2f((u16)(q1.y & 0xffff))
                    + bf2f((u16)(q2.y & 0xffff)) + bf2f((u16)(q3.y & 0xffff));
            acc[3] += bf2f((u16)(q0.y >> 16))    + bf2f((u16)(q1.y >> 16))
                    + bf2f((u16)(q2.y >> 16))    + bf2f((u16)(q3.y >> 16));
            acc[4] += bf2f((u16)(q0.z & 0xffff)) + bf2f((u16)(q1.z & 0xffff))
                    + bf2f((u16)(q2.z & 0xffff)) + bf2f((u16)(q3.z & 0xffff));
            acc[5] += bf2f((u16)(q0.z >> 16))    + bf2f((u16)(q1.z >> 16))
                    + bf2f((u16)(q2.z >> 16))    + bf2f((u16)(q3.z >> 16));
            acc[6] += bf2f((u16)(q0.w & 0xffff)) + bf2f((u16)(q1.w & 0xffff))
                    + bf2f((u16)(q2.w & 0xffff)) + bf2f((u16)(q3.w & 0xffff));
            acc[7] += bf2f((u16)(q0.w >> 16))    + bf2f((u16)(q1.w >> 16))
                    + bf2f((u16)(q2.w >> 16))    + bf2f((u16)(q3.w >> 16));
        }
        for (; t < cnt; ++t) {
            int i0 = __shfl(myn, gbase + t);
            uint4 q0 = *(const uint4*)(x + (size_t)i0 * 128 + f * 8);
            acc[0] += bf2f((u16)(q0.x & 0xffff));
            acc[1] += bf2f((u16)(q0.x >> 16));
            acc[2] += bf2f((u16)(q0.y & 0xffff));
            acc[3] += bf2f((u16)(q0.y >> 16));
            acc[4] += bf2f((u16)(q0.z & 0xffff));
            acc[5] += bf2f((u16)(q0.z >> 16));
            acc[6] += bf2f((u16)(q0.w & 0xffff));
            acc[7] += bf2f((u16)(q0.w >> 16));
        }
    }
    float inv = 1.0f / fmaxf((float)(end - beg), 1.0f);
    u16 o[8];
#pragma unroll
    for (int j = 0; j < 8; ++j) o[j] = f2bf(acc[j] * inv);
    *(uint4*)(out + (size_t)node * 128 + f * 8) = *(const uint4*)o;
}

// ---------------- doc encoder GEMM (f32 A; 128-row block, 32-row wave) ----
__global__ __launch_bounds__(256) void doc_gemm(
    const float* __restrict__ A1f, const u16* __restrict__ W1T,
    const float* __restrict__ bias, u16* __restrict__ out, const int M) {
    __shared__ u16 WS[128 * 128];   // 32 KB
    const int tid = threadIdx.x;
    const int lane = tid & 63, wave = tid >> 6;
    const int r15 = lane & 15, kq = lane >> 4;
    const int rowbase = blockIdx.x * 128 + wave * 32;
    const int m0 = rowbase + r15, m1 = rowbase + 16 + r15;
    const bool v0 = rowbase < M, v1 = rowbase + 16 < M;

    vf32x4 acc0[8], acc1[8];
#pragma unroll
    for (int i = 0; i < 8; ++i) { acc0[i] = (vf32x4)(0.0f); acc1[i] = (vf32x4)(0.0f); }

#pragma unroll
    for (int i = 0; i < 8; ++i) {
        int L = i * 256 + tid;
        int n = L >> 4, bk = L & 15;
        uint4 v = *(const uint4*)(W1T + (size_t)L * 8);
        *(uint4*)(WS + ((size_t)n * 16 + (bk ^ (n & 15))) * 8) = v;
    }
    __syncthreads();

#pragma unroll
    for (int ks = 0; ks < 4; ++ks) {
        vbf16x8 a0 = (vbf16x8)(short)0, a1 = (vbf16x8)(short)0;
        if (v0) {
            const float* p = A1f + (size_t)m0 * 128 + ks * 32 + kq * 8;
            float4 lo = *(const float4*)p, hi = *(const float4*)(p + 4);
            a0[0] = (short)f2bf(lo.x); a0[1] = (short)f2bf(lo.y);
            a0[2] = (short)f2bf(lo.z); a0[3] = (short)f2bf(lo.w);
            a0[4] = (short)f2bf(hi.x); a0[5] = (short)f2bf(hi.y);
            a0[6] = (short)f2bf(hi.z); a0[7] = (short)f2bf(hi.w);
        }
        if (v1) {
            const float* p = A1f + (size_t)m1 * 128 + ks * 32 + kq * 8;
            float4 lo = *(const float4*)p, hi = *(const float4*)(p + 4);
            a1[0] = (short)f2bf(lo.x); a1[1] = (short)f2bf(lo.y);
            a1[2] = (short)f2bf(lo.z); a1[3] = (short)f2bf(lo.w);
            a1[4] = (short)f2bf(hi.x); a1[5] = (short)f2bf(hi.y);
            a1[6] = (short)f2bf(hi.z); a1[7] = (short)f2bf(hi.w);
        }
#pragma unroll
        for (int nt = 0; nt < 8; ++nt) {
            vbf16x8 b = *(const vbf16x8*)(
                WS + ((size_t)(nt * 16 + r15) * 16 + ((ks * 4 + kq) ^ r15)) * 8);
            acc0[nt] = __builtin_amdgcn_mfma_f32_16x16x32_bf16(a0, b, acc0[nt], 0, 0, 0);
            acc1[nt] = __builtin_amdgcn_mfma_f32_16x16x32_bf16(a1, b, acc1[nt], 0, 0, 0);
        }
    }

#pragma unroll
    for (int nt = 0; nt < 8; ++nt) {
        const float bv = bias[nt * 16 + r15];
#pragma unroll
        for (int r = 0; r < 4; ++r) {
            if (v0) out[(size_t)(rowbase + kq * 4 + r) * 128 + nt * 16 + r15] =
                f2bf(acc0[nt][r] + bv);
            if (v1) out[(size_t)(rowbase + 16 + kq * 4 + r) * 128 + nt * 16 + r15] =
                f2bf(acc1[nt][r] + bv);
        }
    }
}

// ------ fused dual-side SAGE conv GEMM (128-row block, 32-row wave) -------
struct SideParams {
    const u16* A1b; const u16* W1T;
    const u16* A2b; const u16* W2T;
    const float* bias; u16* out;
    int M; int do_relu; int nblocks;
};
__global__ __launch_bounds__(256) void conv_gemm2(SideParams sa, SideParams sd) {
    __shared__ u16 WS[128 * 128];   // 32 KB
    const bool isA = (int)blockIdx.x < sa.nblocks;
    SideParams P = isA ? sa : sd;
    const int bx = isA ? blockIdx.x : blockIdx.x - sa.nblocks;
    const int tid = threadIdx.x;
    const int lane = tid & 63, wave = tid >> 6;
    const int r15 = lane & 15, kq = lane >> 4;
    const int rowbase = bx * 128 + wave * 32;
    const int m0 = rowbase + r15, m1 = rowbase + 16 + r15;
    const bool v0 = rowbase < P.M, v1 = rowbase + 16 < P.M;   // M % 16 == 0

    vf32x4 acc0[8], acc1[8];
#pragma unroll
    for (int i = 0; i < 8; ++i) { acc0[i] = (vf32x4)(0.0f); acc1[i] = (vf32x4)(0.0f); }

#pragma unroll
    for (int mat = 0; mat < 2; ++mat) {
        const u16* WT = mat ? P.W2T : P.W1T;
        if (mat) __syncthreads();          // protect WS before overwrite
#pragma unroll
        for (int i = 0; i < 8; ++i) {
            int L = i * 256 + tid;
            int n = L >> 4, bk = L & 15;
            uint4 v = *(const uint4*)(WT + (size_t)L * 8);
            *(uint4*)(WS + ((size_t)n * 16 + (bk ^ (n & 15))) * 8) = v;
        }
        __syncthreads();

        const u16* Ab = mat ? P.A2b : P.A1b;
#pragma unroll
        for (int ks = 0; ks < 4; ++ks) {
            vbf16x8 a0 = (vbf16x8)(short)0, a1 = (vbf16x8)(short)0;
            if (v0) a0 = *(const vbf16x8*)(Ab + (size_t)m0 * 128 + ks * 32 + kq * 8);
            if (v1) a1 = *(const vbf16x8*)(Ab + (size_t)m1 * 128 + ks * 32 + kq * 8);
#pragma unroll
            for (int nt = 0; nt < 8; ++nt) {
                vbf16x8 b = *(const vbf16x8*)(
                    WS + ((size_t)(nt * 16 + r15) * 16 + ((ks * 4 + kq) ^ r15)) * 8);
                acc0[nt] = __builtin_amdgcn_mfma_f32_16x16x32_bf16(a0, b, acc0[nt], 0, 0, 0);
                acc1[nt] = __builtin_amdgcn_mfma_f32_16x16x32_bf16(a1, b, acc1[nt], 0, 0, 0);
            }
        }
    }

#pragma unroll
    for (int nt = 0; nt < 8; ++nt) {
        const float bv = P.bias[nt * 16 + r15];
#pragma unroll
        for (int r = 0; r < 4; ++r) {
            if (v0) {
                float v = acc0[nt][r] + bv;
                if (P.do_relu) v = fmaxf(v, 0.0f);
                P.out[(size_t)(rowbase + kq * 4 + r) * 128 + nt * 16 + r15] = f2bf(v);
            }
            if (v1) {
                float v = acc1[nt][r] + bv;
                if (P.do_relu) v = fmaxf(v, 0.0f);
                P.out[(size_t)(rowbase + 16 + kq * 4 + r) * 128 + nt * 16 + r15] = f2bf(v);
            }
        }
    }
}

// ---------------- edge scorer: pred[e] = dot(od[i0[e]], oa[i1[e]]) --------
__global__ __launch_bounds__(256) void edge_dot(
    const u16* __restrict__ od, const u16* __restrict__ oa,
    const int* __restrict__ i0, const int* __restrict__ i1,
    float* __restrict__ pred, int EL) {
    int gid = blockIdx.x * 256 + threadIdx.x;
    if (gid >= EL * 16) return;
    int e = gid >> 4, f = gid & 15;
    uint4 x = *(const uint4*)(od + (size_t)i0[e] * 128 + f * 8);
    uint4 y = *(const uint4*)(oa + (size_t)i1[e] * 128 + f * 8);
    float s = 0.0f;
    s += bf2f((u16)(x.x & 0xffff)) * bf2f((u16)(y.x & 0xffff));
    s += bf2f((u16)(x.x >> 16))    * bf2f((u16)(y.x >> 16));
    s += bf2f((u16)(x.y & 0xffff)) * bf2f((u16)(y.y & 0xffff));
    s += bf2f((u16)(x.y >> 16))    * bf2f((u16)(y.y >> 16));
    s += bf2f((u16)(x.z & 0xffff)) * bf2f((u16)(y.z & 0xffff));
    s += bf2f((u16)(x.z >> 16))    * bf2f((u16)(y.z >> 16));
    s += bf2f((u16)(x.w & 0xffff)) * bf2f((u16)(y.w & 0xffff));
    s += bf2f((u16)(x.w >> 16))    * bf2f((u16)(y.w >> 16));
    s += __shfl_xor(s, 1);
    s += __shfl_xor(s, 2);
    s += __shfl_xor(s, 4);
    s += __shfl_xor(s, 8);
    if (f == 0) pred[e] = s;
}

extern "C" void kernel_launch(void* const* d_in, const int* in_sizes, int n_in,
                              void* d_out, int out_size, void* d_ws, size_t ws_size,
                              hipStream_t stream) {
    const float* doc_x    = (const float*)d_in[0];
    const int*   auth_id  = (const int*)d_in[1];
    const int*   eidx     = (const int*)d_in[2];
    const int*   elidx    = (const int*)d_in[3];
    const float* W_doc    = (const float*)d_in[4];
    const float* b_doc    = (const float*)d_in[5];
    const float* emb      = (const float*)d_in[6];
    const float* c1_da_Wl = (const float*)d_in[7];
    const float* c1_da_bl = (const float*)d_in[8];
    const float* c1_da_Wr = (const float*)d_in[9];
    const float* c1_ad_Wl = (const float*)d_in[10];
    const float* c1_ad_bl = (const float*)d_in[11];
    const float* c1_ad_Wr = (const float*)d_in[12];
    const float* c2_da_Wl = (const float*)d_in[13];
    const float* c2_da_bl = (const float*)d_in[14];
    const float* c2_da_Wr = (const float*)d_in[15];
    const float* c2_ad_Wl = (const float*)d_in[16];
    const float* c2_ad_bl = (const float*)d_in[17];
    const float* c2_ad_Wr = (const float*)d_in[18];

    const int ND = in_sizes[0] / 128;
    const int NA = in_sizes[1];
    const int E  = in_sizes[2] / 2;
    const int EL = in_sizes[3] / 2;
    const int* e_src = eidx;        // doc endpoints
    const int* e_dst = eidx + E;    // author endpoints
    const int NBD = (ND + 255) / 256, NBA = (NA + 255) / 256;
    const int BA = (NA + 127) / 128, BD = (ND + 127) / 128;   // 128-row tiles
    const int histB = (E + 255) / 256;
    const int prepB = 576 + (NA * 16 + 255) / 256;

    // ---- workspace layout ----
    char* base = (char*)d_ws;
    size_t off = 0;
    auto alloc = [&](size_t bytes) {
        void* p = base + off;
        off = (off + bytes + 255) & ~(size_t)255;
        return p;
    };
    u16*  xdoc  = (u16*)alloc((size_t)ND * 128 * 2);   // later reused as o_d
    u16*  xauth = (u16*)alloc((size_t)NA * 128 * 2);   // later reused as o_a
    u16*  hd    = (u16*)alloc((size_t)ND * 128 * 2);
    u16*  ha    = (u16*)alloc((size_t)NA * 128 * 2);
    u16*  aggA  = (u16*)alloc((size_t)NA * 128 * 2);
    u16*  aggD  = (u16*)alloc((size_t)ND * 128 * 2);
    u16*  wt    = (u16*)alloc((size_t)9 * 128 * 128 * 2);
    int*  cnt   = (int*)alloc((size_t)(ND + NA) * 4);
    int*  incl  = (int*)alloc((size_t)(ND + NA) * 4);
    int*  bs    = (int*)alloc((size_t)(NBD + NBA) * 4);
    int*  offs_d = (int*)alloc((size_t)(ND + 1) * 4);
    int*  offs_a = (int*)alloc((size_t)(NA + 1) * 4);
    int*  cur_d = (int*)alloc((size_t)(ND + 1) * 4);
    int*  cur_a = (int*)alloc((size_t)(NA + 1) * 4);
    int*  nbr_d = (int*)alloc((size_t)E * 4);
    int*  nbr_a = (int*)alloc((size_t)E * 4);
    (void)ws_size; (void)n_in; (void)out_size;
    u16* od = xdoc;   // layer-2 outputs overwrite layer-0 features
    u16* oa = xauth;

    TPack tp;
    const float* srcs[9] = {W_doc, c1_da_Wl, c1_da_Wr, c1_ad_Wl, c1_ad_Wr,
                            c2_da_Wl, c2_da_Wr, c2_ad_Wl, c2_ad_Wr};
    for (int i = 0; i < 9; ++i) { tp.src[i] = srcs[i]; tp.dst[i] = wt + (size_t)i * 16384; }
    const u16 *WTdoc = wt, *WT_c1daL = wt + 16384, *WT_c1daR = wt + 2 * 16384,
              *WT_c1adL = wt + 3 * 16384, *WT_c1adR = wt + 4 * 16384,
              *WT_c2daL = wt + 5 * 16384, *WT_c2daR = wt + 6 * 16384,
              *WT_c2adL = wt + 7 * 16384, *WT_c2adR = wt + 8 * 16384;

    // ---- CSR count + prep (one dispatch) ----
    hipMemsetAsync(cnt, 0, (size_t)(ND + NA) * 4, stream);
    mega_hist_prep<<<prepB + histB, 256, 0, stream>>>(
        tp, emb, auth_id, xauth, NA, e_src, e_dst, cnt, ND, E, prepB);

    // ---- offsets + cursor seed ----
    scan1b<<<NBD + NBA, 256, 0, stream>>>(cnt, incl, bs, ND, NA, NBD);
    scan2b<<<1, 256, 0, stream>>>(bs, NBD, NBA);
    scan3b<<<NBD + NBA, 256, 0, stream>>>(
        incl, bs, offs_d, offs_a, cur_d, cur_a, ND, NA, NBD);

    // ---- CSR fill (no LDS, high occupancy) ----
    fill_kernel<<<histB, 256, 0, stream>>>(
        e_src, e_dst, cur_d, cur_a, nbr_d, nbr_a, E);

    // ---- doc encoder ----
    doc_gemm<<<BD, 256, 0, stream>>>(doc_x, WTdoc, b_doc, xdoc, ND);

    const int aggGrid = ((NA + ND) * 16 + 255) / 256;

    // ---- layer 1 (relu) ----
    agg_mean2<<<aggGrid, 256, 0, stream>>>(
        xdoc, offs_a, nbr_a, aggA, NA, xauth, offs_d, nbr_d, aggD, ND);
    {
        SideParams sa = {aggA, WT_c1daL, xauth, WT_c1daR, c1_da_bl, ha, NA, 1, BA};
        SideParams sd = {aggD, WT_c1adL, xdoc,  WT_c1adR, c1_ad_bl, hd, ND, 1, BD};
        conv_gemm2<<<BA + BD, 256, 0, stream>>>(sa, sd);
    }

    // ---- layer 2 ----
    agg_mean2<<<aggGrid, 256, 0, stream>>>(
        hd, offs_a, nbr_a, aggA, NA, ha, offs_d, nbr_d, aggD, ND);
    {
        SideParams sa = {aggA, WT_c2daL, ha, WT_c2daR, c2_da_bl, oa, NA, 0, BA};
        SideParams sd = {aggD, WT_c2adL, hd, WT_c2adR, c2_ad_bl, od, ND, 0, BD};
        conv_gemm2<<<BA + BD, 256, 0, stream>>>(sa, sd);
    }

    // ---- edge scorer ----
    edge_dot<<<(EL * 16 + 255) / 256, 256, 0, stream>>>(
        od, oa, elidx, elidx + EL, (float*)d_out, EL);
}